// Round 1
// 261.182 us; speedup vs baseline: 1.0859x; 1.0859x over previous
//
#include <hip/hip_runtime.h>

typedef _Float16 half_t;
typedef _Float16 half8  __attribute__((ext_vector_type(8)));
typedef _Float16 half2v __attribute__((ext_vector_type(2)));
typedef float    floatx4 __attribute__((ext_vector_type(4)));

#define MFMA16(a, b, c) __builtin_amdgcn_mfma_f32_16x16x32_f16((a), (b), (c), 0, 0, 0)

// ---------------------------------------------------------------------------
// Merged prep: [blocks 0..4607] fc1 w fp32->fp16; [4608..4679] conv2 w
// transpose->fp16; [4680] GMM Sigma_inv + det_scale.
// GMM block REWRITTEN spill-proof: previous version held Rr[100]+Li[100]+Dl[10]
// (~210 live floats) in ONE thread -> near-certain scratch spill -> suspected
// hidden ~100us. Now: raw staged in LDS, L^-1 solved column-parallel (100
// threads x v[10] regs, all static indices), Sigma_inv formed from LDS.
// ---------------------------------------------------------------------------
__global__ void k_prep(const float* __restrict__ fw1, half_t* __restrict__ W1h,
                       const float* __restrict__ w2, half_t* __restrict__ W2T,
                       const float* __restrict__ raw, float* __restrict__ Sinv,
                       float* __restrict__ dets) {
    __shared__ float s_raw[1000];
    __shared__ float s_Li[1000];
    __shared__ float s_Dinv[100];
    const int blk = blockIdx.x;
    const int t = threadIdx.x;
    if (blk < 4608) {
        const int i = blk * 256 + t;  // 1179648 exact
        W1h[i] = (half_t)fw1[i];
    } else if (blk < 4680) {
        const int i = (blk - 4608) * 256 + t;
        if (i < 18432) {
            const int tap = i / 2048;
            const int r = i - tap * 2048;
            const int co = r >> 5;
            const int ci = r & 31;
            W2T[i] = (half_t)w2[(co * 32 + ci) * 9 + tap];
        }
    } else {
        for (int i = t; i < 1000; i += 256) s_raw[i] = raw[i];
        __syncthreads();
        if (t < 100) {
            // thread (k,j): column j of L^{-1} for component k.  L v = e_j.
            const int k = t / 10;
            const int j = t - k * 10;
            float v[10];
#pragma unroll
            for (int i = 0; i < 10; ++i) {
                float s = (i == j) ? 1.0f : 0.0f;
#pragma unroll
                for (int mm = 0; mm < 10; ++mm)
                    if (mm < i) s -= s_raw[k * 100 + i * 10 + mm] * v[mm];
                v[i] = s;  // v[i]=0 for i<j automatically
            }
#pragma unroll
            for (int a = 0; a < 10; ++a) s_Li[k * 100 + a * 10 + j] = v[a];
        } else if (t < 110) {
            const int k = t - 100;
            float prod = 1.0f;
#pragma unroll
            for (int a = 0; a < 10; ++a) {
                const float rd = s_raw[k * 100 + a * 10 + a];
                const float dv = rd * rd + 1e-4f;
                s_Dinv[k * 10 + a] = 1.0f / dv;
                prod *= dv;
            }
            dets[k] = rsqrtf(prod);
        }
        __syncthreads();
        for (int idx = t; idx < 1000; idx += 256) {
            const int k = idx / 100;
            const int r = idx - k * 100;
            const int ii = r / 10;
            const int jj = r - ii * 10;
            float s = 0.0f;
#pragma unroll
            for (int a = 0; a < 10; ++a)
                s += s_Li[k * 100 + a * 10 + ii] * s_Dinv[k * 10 + a] *
                     s_Li[k * 100 + a * 10 + jj];
            Sinv[idx] = s;
        }
    }
}

// ---------------------------------------------------------------------------
// Fused conv1(fp32) + conv2(MFMA f16) + bias/ReLU/2x2-maxpool.
// Restructured for occupancy (was 2 waves/SIMD, 21%):
//  - wave owns a ct-PAIR (32 of 64 co) -> bf[9][2] = 72 VGPR (was 144) and
//    18 M-tiles of 16px. A-frag LDS traffic doubles (pipe has headroom);
//    regs ~130 -> 3 blocks/CU via __launch_bounds__(256,3).
//  - M-row ordering chosen so one lane's 4 acc regs = one 2x2 pool cell:
//    maxpool = 3 VALU max, ZERO shuffles, all 64 lanes store.
//  - s_h1 re-laid as [pix][32ci] with XOR swizzle (byte ^= (pix&7)<<4):
//    每 8-lane octet of conv1-write and conv2-read hits 8 distinct bank
//    quads (verified algebraically) -> conflict-free b128.
// ---------------------------------------------------------------------------
__global__ __launch_bounds__(256, 3) void k_convs(
    const float* __restrict__ x, const float* __restrict__ w1,
    const float* __restrict__ b1, const float* __restrict__ b2,
    const half_t* __restrict__ W2T, half_t* __restrict__ h2p) {
    __shared__ float s_x[784];
    __shared__ float s_w1[288];
    __shared__ float s_b1[32];
    __shared__ float s_b2[64];
    __shared__ __align__(16) half_t s_h1[21632];  // 676 pix x 32 ci, swizzled

    const int t = threadIdx.x;
    const int b = blockIdx.x;

    for (int i = t; i < 784; i += 256) s_x[i] = x[(size_t)b * 784 + i];
    for (int i = t; i < 288; i += 256) s_w1[i] = w1[i];
    if (t < 32) s_b1[t] = b1[t];
    if (t < 64) s_b2[t] = b2[t];
    __syncthreads();

    const int w = t >> 6;
    const int ln = t & 63;
    const int n16 = ln & 15;
    const int q = ln >> 4;

    // ---- conv1: wave g owns ci-group g (8 channels), lanes sweep 676 px ----
    {
        float wr[8][9], br[8];
#pragma unroll
        for (int j = 0; j < 8; ++j) {
            br[j] = s_b1[w * 8 + j];
#pragma unroll
            for (int k = 0; k < 9; ++k) wr[j][k] = s_w1[(w * 8 + j) * 9 + k];
        }
        for (int p = ln; p < 676; p += 64) {
            const int yy = p / 26;
            const int xx = p - yy * 26;
            float win[9];
#pragma unroll
            for (int r = 0; r < 3; ++r)
#pragma unroll
                for (int c = 0; c < 3; ++c) win[r * 3 + c] = s_x[(yy + r) * 28 + xx + c];
            half8 hv;
#pragma unroll
            for (int j = 0; j < 8; ++j) {
                float a = br[j];
#pragma unroll
                for (int k = 0; k < 9; ++k) a = fmaf(win[k], wr[j][k], a);
                hv[j] = (half_t)fmaxf(a, 0.0f);
            }
            const int off = ((p << 6) + (w << 4)) ^ ((p & 7) << 4);
            *(half8*)((char*)s_h1 + off) = hv;
        }
    }

    // ---- preload this wave's 2 co-tiles of conv2 weights (72 VGPR) --------
    const int cp = w & 1;  // co tiles {2cp, 2cp+1}
    half8 bf[9][2];
#pragma unroll
    for (int tap = 0; tap < 9; ++tap)
#pragma unroll
        for (int cc = 0; cc < 2; ++cc)
            bf[tap][cc] = *(const half8*)(W2T +
                ((tap * 64 + (2 * cp + cc) * 16 + n16) * 32 + q * 8));

    __syncthreads();

#pragma unroll
    for (int tap = 0; tap < 9; ++tap)
#pragma unroll
        for (int cc = 0; cc < 2; ++cc)
            asm volatile("" : "+v"(bf[tap][cc]));  // pin: no remat, no sink

    // row m (0..15) -> pixel: cell=m>>2 (py'=cell&1, px'=cell>>1),
    // quad=m&3 (dy=quad>>1, dx=quad&1). C-side: lane's rows 4q+reg -> cell=q.
    const int am = ln & 15;
    const int aly = 2 * ((am >> 2) & 1) + ((am >> 1) & 1);
    const int alx = 2 * (am >> 3) + (am & 1);
    const int qoff = q << 4;
    const char* h1b = (const char*)s_h1;
    const int mhalf = w >> 1;

    for (int i = 0; i < 18; ++i) {
        const int mt = mhalf * 18 + i;   // 36 tiles of 4x4 conv2 px (2x2 pool)
        const int tY = mt / 6;
        const int tX = mt - tY * 6;
        const int ybase = 4 * tY + aly;
        const int xbase = 4 * tX + alx;
        floatx4 acc0 = {0.f, 0.f, 0.f, 0.f};
        floatx4 acc1 = {0.f, 0.f, 0.f, 0.f};
#pragma unroll
        for (int tap = 0; tap < 9; ++tap) {
            const int ky = tap / 3;
            const int kx = tap - ky * 3;
            const int pix = (ybase + ky) * 26 + xbase + kx;
            const int off = ((pix << 6) + qoff) ^ ((pix & 7) << 4);
            const half8 af = *(const half8*)(h1b + off);
            acc0 = MFMA16(af, bf[tap][0], acc0);
            acc1 = MFMA16(af, bf[tap][1], acc1);
        }
        // lane owns pool cell q of this tile: pool = max over its 4 acc regs
        const int poolY = 2 * tY + (q & 1);
        const int poolX = 2 * tX + (q >> 1);
        const float v0 = fmaxf(fmaxf(acc0[0], acc0[1]), fmaxf(acc0[2], acc0[3]));
        const float v1 = fmaxf(fmaxf(acc1[0], acc1[1]), fmaxf(acc1[2], acc1[3]));
        const int co0 = (2 * cp) * 16 + n16;
        const int co1 = co0 + 16;
        const size_t base = (size_t)b * 9216 + poolY * 12 + poolX;
        h2p[base + (size_t)co0 * 144] = (half_t)fmaxf(v0 + s_b2[co0], 0.0f);
        h2p[base + (size_t)co1 * 144] = (half_t)fmaxf(v1 + s_b2[co1], 0.0f);
    }
}

// ---------------------------------------------------------------------------
// fc1: C[4096,128] = A[4096,9216](fp16) x W^T. Split-K=16 (chunk 576).
// LDS-free, barrier-free. Grid 32x16 = 512 blocks. fp16 partials.
// ---------------------------------------------------------------------------
__global__ __launch_bounds__(256) void k_fc1(const half_t* __restrict__ A,
                                             const half_t* __restrict__ W,
                                             half_t* __restrict__ part) {
    const int t = threadIdx.x;
    const int mb = blockIdx.x;  // 0..31
    const int kb = blockIdx.y;  // 0..15
    const int w = t >> 6, ln = t & 63, n16 = ln & 15, q = ln >> 4;

    const half_t* a0 = A + (size_t)(mb * 128 + w * 32 + n16) * 9216 + kb * 576 + q * 8;
    const half_t* a1 = a0 + (size_t)16 * 9216;
    const half_t* wp = W + (size_t)n16 * 9216 + kb * 576 + q * 8;

    floatx4 acc[2][8];
#pragma unroll
    for (int s = 0; s < 2; ++s)
#pragma unroll
        for (int nt = 0; nt < 8; ++nt) acc[s][nt] = (floatx4){0.f, 0.f, 0.f, 0.f};

    for (int kt = 0; kt < 18; ++kt) {
        const int ko = kt * 32;
        half8 af0 = *(const half8*)(a0 + ko);
        half8 af1 = *(const half8*)(a1 + ko);
#pragma unroll
        for (int nt = 0; nt < 8; ++nt) {
            half8 bfr = *(const half8*)(wp + (size_t)nt * 16 * 9216 + ko);
            acc[0][nt] = MFMA16(af0, bfr, acc[0][nt]);
            acc[1][nt] = MFMA16(af1, bfr, acc[1][nt]);
        }
    }
    const int rowbase = mb * 128 + w * 32;
#pragma unroll
    for (int s = 0; s < 2; ++s)
#pragma unroll
        for (int nt = 0; nt < 8; ++nt)
#pragma unroll
            for (int r = 0; r < 4; ++r) {
                const int row = rowbase + s * 16 + q * 4 + r;
                const int col = nt * 16 + n16;
                part[(size_t)kb * 524288 + (size_t)row * 128 + col] = (half_t)acc[s][nt][r];
            }
}

// ---------------------------------------------------------------------------
// fc1 split-K reduction + bias + ReLU -> fp16 h3
// ---------------------------------------------------------------------------
__global__ void k_fc1red(const half_t* __restrict__ part, const float* __restrict__ b,
                         half_t* __restrict__ h3) {
    const int idx = blockIdx.x * 256 + threadIdx.x;  // 524288 exact
    const int col = idx & 127;
    float s = 0.0f;
#pragma unroll
    for (int j = 0; j < 16; ++j) s += (float)part[(size_t)j * 524288 + idx];
    s = fmaxf(s + b[col], 0.0f);
    h3[idx] = (half_t)s;
}

// ---------------------------------------------------------------------------
// fc2 + GMM posterior (fp32). One thread per sample.
// ---------------------------------------------------------------------------
__global__ __launch_bounds__(256) void k_fc2gmm(
    const half_t* __restrict__ h3, const float* __restrict__ fw,
    const float* __restrict__ fb, const float* __restrict__ cent,
    const float* __restrict__ Sinv, const float* __restrict__ dets,
    float* __restrict__ out) {
    __shared__ float sw[1280];
    __shared__ float sb[10];
    __shared__ float sc[100];
    __shared__ float ss[1000];
    __shared__ float sd[10];
    const int t = threadIdx.x;
    for (int i = t; i < 1280; i += 256) sw[i] = fw[i];
    if (t < 10) sb[t] = fb[t];
    if (t < 100) sc[t] = cent[t];
    for (int i = t; i < 1000; i += 256) ss[i] = Sinv[i];
    if (t < 10) sd[t] = dets[t];
    __syncthreads();

    const int bidx = blockIdx.x * 256 + t;  // 4096 samples exact
    half2v hh[64];
    const half2v* hp = (const half2v*)(h3 + (size_t)bidx * 128);
#pragma unroll
    for (int i = 0; i < 64; ++i) hh[i] = hp[i];

    float y[10];
#pragma unroll
    for (int o = 0; o < 10; ++o) {
        float a = sb[o];
#pragma unroll
        for (int k = 0; k < 64; ++k) {
            a = fmaf((float)hh[k][0], sw[o * 128 + 2 * k], a);
            a = fmaf((float)hh[k][1], sw[o * 128 + 2 * k + 1], a);
        }
        y[o] = a;
    }

    float expo[10];
    float mx = -3.402823466e38f;
#pragma unroll
    for (int k = 0; k < 10; ++k) {
        float d[10];
#pragma unroll
        for (int j = 0; j < 10; ++j) d[j] = y[j] - sc[k * 10 + j];
        float s = 0.0f;
#pragma unroll
        for (int i = 0; i < 10; ++i) {
            float r = 0.0f;
#pragma unroll
            for (int j = 0; j < 10; ++j) r = fmaf(ss[k * 100 + i * 10 + j], d[j], r);
            s = fmaf(d[i], r, s);
        }
        expo[k] = -0.5f * s;
        mx = fmaxf(mx, expo[k]);
    }
    float num[10];
    float sum = 0.0f;
#pragma unroll
    for (int k = 0; k < 10; ++k) {
        num[k] = sd[k] * __expf(expo[k] - mx);
        sum += num[k];
    }
    const float inv = 1.0f / sum;
#pragma unroll
    for (int k = 0; k < 10; ++k) out[(size_t)bidx * 10 + k] = num[k] * inv;
}

// ---------------------------------------------------------------------------
extern "C" void kernel_launch(void* const* d_in, const int* in_sizes, int n_in,
                              void* d_out, int out_size, void* d_ws, size_t ws_size,
                              hipStream_t stream) {
    const float* x = (const float*)d_in[0];
    const float* w1 = (const float*)d_in[1];
    const float* b1 = (const float*)d_in[2];
    const float* w2 = (const float*)d_in[3];
    const float* b2 = (const float*)d_in[4];
    const float* fw1 = (const float*)d_in[5];
    const float* fb1 = (const float*)d_in[6];
    const float* fw2 = (const float*)d_in[7];
    const float* fb2 = (const float*)d_in[8];
    const float* cen = (const float*)d_in[9];
    const float* raw = (const float*)d_in[10];
    float* out = (float*)d_out;

    char* ws = (char*)d_ws;
    half_t* W2T = (half_t*)(ws);                 //    36,864 B
    half_t* W1h = (half_t*)(ws + 36864);         // 2,359,296 B
    half_t* h2p = (half_t*)(ws + 2396160);       // 75,497,472 B
    half_t* part = (half_t*)(ws + 77893632);     // 16,777,216 B (16 x 524288 fp16)
    half_t* h3h = (half_t*)(ws + 94670848);      // 1,048,576 B
    float* gS = (float*)(ws + 95719424);         //     4,000 B
    float* gD = (float*)(ws + 95723424);         //        40 B  (total ~95.7 MB)

    k_prep<<<4681, 256, 0, stream>>>(fw1, W1h, w2, W2T, raw, gS, gD);
    k_convs<<<4096, 256, 0, stream>>>(x, w1, b1, b2, W2T, h2p);
    k_fc1<<<dim3(32, 16), 256, 0, stream>>>(h2p, W1h, part);
    k_fc1red<<<2048, 256, 0, stream>>>(part, fb1, h3h);
    k_fc2gmm<<<16, 256, 0, stream>>>(h3h, fw2, fb2, cen, gS, gD, out);
}

// Round 2
// 241.974 us; speedup vs baseline: 1.1721x; 1.0794x over previous
//
#include <hip/hip_runtime.h>

typedef _Float16 half_t;
typedef _Float16 half8  __attribute__((ext_vector_type(8)));
typedef _Float16 half2v __attribute__((ext_vector_type(2)));
typedef float    floatx4 __attribute__((ext_vector_type(4)));

#define MFMA16(a, b, c) __builtin_amdgcn_mfma_f32_16x16x32_f16((a), (b), (c), 0, 0, 0)

// ---------------------------------------------------------------------------
// Merged prep: [blocks 0..4607] fc1 w fp32->fp16; [4608..4679] conv2 w
// transpose->fp16; [4680] GMM Sigma_inv + det_scale (spill-proof parallel
// forward-substitution, round-1 version).
// ---------------------------------------------------------------------------
__global__ void k_prep(const float* __restrict__ fw1, half_t* __restrict__ W1h,
                       const float* __restrict__ w2, half_t* __restrict__ W2T,
                       const float* __restrict__ raw, float* __restrict__ Sinv,
                       float* __restrict__ dets) {
    __shared__ float s_raw[1000];
    __shared__ float s_Li[1000];
    __shared__ float s_Dinv[100];
    const int blk = blockIdx.x;
    const int t = threadIdx.x;
    if (blk < 4608) {
        const int i = blk * 256 + t;  // 1179648 exact
        W1h[i] = (half_t)fw1[i];
    } else if (blk < 4680) {
        const int i = (blk - 4608) * 256 + t;
        if (i < 18432) {
            const int tap = i / 2048;
            const int r = i - tap * 2048;
            const int co = r >> 5;
            const int ci = r & 31;
            W2T[i] = (half_t)w2[(co * 32 + ci) * 9 + tap];
        }
    } else {
        for (int i = t; i < 1000; i += 256) s_raw[i] = raw[i];
        __syncthreads();
        if (t < 100) {
            // thread (k,j): column j of L^{-1} for component k.  L v = e_j.
            const int k = t / 10;
            const int j = t - k * 10;
            float v[10];
#pragma unroll
            for (int i = 0; i < 10; ++i) {
                float s = (i == j) ? 1.0f : 0.0f;
#pragma unroll
                for (int mm = 0; mm < 10; ++mm)
                    if (mm < i) s -= s_raw[k * 100 + i * 10 + mm] * v[mm];
                v[i] = s;  // v[i]=0 for i<j automatically
            }
#pragma unroll
            for (int a = 0; a < 10; ++a) s_Li[k * 100 + a * 10 + j] = v[a];
        } else if (t < 110) {
            const int k = t - 100;
            float prod = 1.0f;
#pragma unroll
            for (int a = 0; a < 10; ++a) {
                const float rd = s_raw[k * 100 + a * 10 + a];
                const float dv = rd * rd + 1e-4f;
                s_Dinv[k * 10 + a] = 1.0f / dv;
                prod *= dv;
            }
            dets[k] = rsqrtf(prod);
        }
        __syncthreads();
        for (int idx = t; idx < 1000; idx += 256) {
            const int k = idx / 100;
            const int r = idx - k * 100;
            const int ii = r / 10;
            const int jj = r - ii * 10;
            float s = 0.0f;
#pragma unroll
            for (int a = 0; a < 10; ++a)
                s += s_Li[k * 100 + a * 10 + ii] * s_Dinv[k * 10 + a] *
                     s_Li[k * 100 + a * 10 + jj];
            Sinv[idx] = s;
        }
    }
}

// ---------------------------------------------------------------------------
// Fused conv1(fp32) + conv2(MFMA f16) + bias/ReLU/2x2-maxpool.
// Round-2 restructure: LDS-read-count attack. Round-1 PMC showed the LDS
// pipe ~75% busy (648 b128 reads/block @ ~19cyc each incl. ~11cyc conflict,
// conflict cost layout-insensitive across rounds 0/1) -> cut READ COUNT.
//   - A-row index of mfma_16x16x32 = lane&15 = x-position. Read one input
//     row of 16px per (y,kx): the kx tap-shift is absorbed into the READ
//     BASE (pixel granularity); the 3 ky taps reuse the same fragment into
//     3 ring accumulators (ky selects WHICH out-row; row index unchanged).
//     78 reads/wave vs 162 (-52%). MFMA 324->432/wave (edge waste; pipe
//     has 3x headroom). Tap order per out-row stays 0..8 -> bit-identical.
//   - Rolling-pointer addressing (imm offsets 0/64/128): no per-tap addr
//     VALU, no XOR swizzle (measured useless for conflicts).
//   - Pool x-pairs land in one lane's acc regs (C rows 4q+{0,1},{2,3}):
//     3 fmax + y-pair buffer, zero shuffles.
//   - Ring slots rotated by MACRO POSITION (static indices, rule #20).
// s_h1: linear [pix 0..687][32ci] (wrap-overreads stay in-bounds; 676..687
// zeroed). 44KB LDS -> still 3 blocks/CU.
// ---------------------------------------------------------------------------
__global__ __launch_bounds__(256, 3) void k_convs(
    const float* __restrict__ x, const float* __restrict__ w1,
    const float* __restrict__ b1, const float* __restrict__ b2,
    const half_t* __restrict__ W2T, half_t* __restrict__ h2p) {
    __shared__ float s_x[784];
    __shared__ float s_w1[288];
    __shared__ float s_b1[32];
    __shared__ float s_b2[64];
    __shared__ __align__(16) half_t s_h1[688 * 32];  // 44032 B

    const int t = threadIdx.x;
    const int b = blockIdx.x;

    for (int i = t; i < 784; i += 256) s_x[i] = x[(size_t)b * 784 + i];
    for (int i = t; i < 288; i += 256) s_w1[i] = w1[i];
    if (t < 32) s_b1[t] = b1[t];
    if (t < 64) s_b2[t] = b2[t];
    if (t < 384) s_h1[21632 + t] = (half_t)0.0f;  // zero the wrap tail
    __syncthreads();

    const int w = t >> 6;
    const int ln = t & 63;
    const int n16 = ln & 15;
    const int q = ln >> 4;

    // ---- conv1: wave g owns ci-group g (8 channels), lanes sweep 676 px ----
    {
        float wr[8][9], br[8];
#pragma unroll
        for (int j = 0; j < 8; ++j) {
            br[j] = s_b1[w * 8 + j];
#pragma unroll
            for (int k = 0; k < 9; ++k) wr[j][k] = s_w1[(w * 8 + j) * 9 + k];
        }
        for (int p = ln; p < 676; p += 64) {
            const int yy = p / 26;
            const int xx = p - yy * 26;
            float win[9];
#pragma unroll
            for (int r = 0; r < 3; ++r)
#pragma unroll
                for (int c = 0; c < 3; ++c) win[r * 3 + c] = s_x[(yy + r) * 28 + xx + c];
            half8 hv;
#pragma unroll
            for (int j = 0; j < 8; ++j) {
                float a = br[j];
#pragma unroll
                for (int k = 0; k < 9; ++k) a = fmaf(win[k], wr[j][k], a);
                hv[j] = (half_t)fmaxf(a, 0.0f);
            }
            *(half8*)((char*)s_h1 + ((p << 6) + (w << 4))) = hv;
        }
    }

    // ---- preload this wave's 2 co-tiles of conv2 weights (72 VGPR) --------
    const int cp = w & 1;   // co half: co = cp*32 + cc*16 + n16
    const int st = w >> 1;  // x-strip: out-x base 16*st
    half8 bf[9][2];
#pragma unroll
    for (int tap = 0; tap < 9; ++tap)
#pragma unroll
        for (int cc = 0; cc < 2; ++cc)
            bf[tap][cc] = *(const half8*)(W2T +
                ((tap * 64 + (2 * cp + cc) * 16 + n16) * 32 + q * 8));

    __syncthreads();

#pragma unroll
    for (int tap = 0; tap < 9; ++tap)
#pragma unroll
        for (int cc = 0; cc < 2; ++cc)
            asm volatile("" : "+v"(bf[tap][cc]));  // pin: no remat, no sink

    // lane reads pixel p = y*26 + 16*st + kx + n16, ci-octet q:
    // byte = p*64 + q*16; rolling pointer, +1664/row, kx at imm 0/64/128.
    const char* rp = (const char*)s_h1 + (((n16 + 16 * st) << 6) + (q << 4));

    const float bb0 = s_b2[cp * 32 + n16];
    const float bb1 = s_b2[cp * 32 + 16 + n16];
    half_t* outp = h2p + (size_t)b * 9216 + (size_t)(cp * 32 + n16) * 144 +
                   8 * st + 2 * q;
    const bool dostore = (st == 0) | (q < 2);  // strip1 valid poolX 8..11

    const floatx4 z4 = {0.f, 0.f, 0.f, 0.f};
    floatx4 sl0[2] = {z4, z4}, sl1[2] = {z4, z4}, sl2[2] = {z4, z4};
    float yb00 = 0.f, yb01 = 0.f, yb10 = 0.f, yb11 = 0.f;

#define RETIRE(YO, AC)                                                        \
    do {                                                                      \
        const float p0 = fmaxf(AC[0][0], AC[0][1]);                           \
        const float p1 = fmaxf(AC[0][2], AC[0][3]);                           \
        const float r0 = fmaxf(AC[1][0], AC[1][1]);                           \
        const float r1 = fmaxf(AC[1][2], AC[1][3]);                           \
        if (((YO) & 1) == 0) {                                                \
            yb00 = p0; yb01 = p1; yb10 = r0; yb11 = r1;                       \
        } else if (dostore) {                                                 \
            half2v h0, h1v;                                                   \
            h0[0] = (half_t)fmaxf(fmaxf(yb00, p0) + bb0, 0.0f);               \
            h0[1] = (half_t)fmaxf(fmaxf(yb01, p1) + bb0, 0.0f);               \
            h1v[0] = (half_t)fmaxf(fmaxf(yb10, r0) + bb1, 0.0f);              \
            h1v[1] = (half_t)fmaxf(fmaxf(yb11, r1) + bb1, 0.0f);              \
            half_t* op = outp + ((YO) >> 1) * 12;                             \
            *(half2v*)(op) = h0;                                              \
            *(half2v*)(op + 2304) = h1v;                                      \
        }                                                                     \
        AC[0] = z4; AC[1] = z4;                                               \
    } while (0)

#define CSTEP(Y_, A0, A1, A2)                                                 \
    do {                                                                      \
        const int y_ = (Y_);                                                  \
        if (y_ < 26) {                                                        \
            const half8 f0 = *(const half8*)(rp);                             \
            const half8 f1 = *(const half8*)(rp + 64);                        \
            const half8 f2 = *(const half8*)(rp + 128);                       \
            if (y_ <= 23) { /* ky=0: taps 0..2 -> out-row y */                \
                A0[0] = MFMA16(f0, bf[0][0], A0[0]);                          \
                A0[1] = MFMA16(f0, bf[0][1], A0[1]);                          \
                A0[0] = MFMA16(f1, bf[1][0], A0[0]);                          \
                A0[1] = MFMA16(f1, bf[1][1], A0[1]);                          \
                A0[0] = MFMA16(f2, bf[2][0], A0[0]);                          \
                A0[1] = MFMA16(f2, bf[2][1], A0[1]);                          \
            }                                                                 \
            if (y_ >= 1 && y_ <= 24) { /* ky=1: taps 3..5 -> out-row y-1 */   \
                A1[0] = MFMA16(f0, bf[3][0], A1[0]);                          \
                A1[1] = MFMA16(f0, bf[3][1], A1[1]);                          \
                A1[0] = MFMA16(f1, bf[4][0], A1[0]);                          \
                A1[1] = MFMA16(f1, bf[4][1], A1[1]);                          \
                A1[0] = MFMA16(f2, bf[5][0], A1[0]);                          \
                A1[1] = MFMA16(f2, bf[5][1], A1[1]);                          \
            }                                                                 \
            if (y_ >= 2) { /* ky=2: taps 6..8 -> out-row y-2, then retire */  \
                A2[0] = MFMA16(f0, bf[6][0], A2[0]);                          \
                A2[1] = MFMA16(f0, bf[6][1], A2[1]);                          \
                A2[0] = MFMA16(f1, bf[7][0], A2[0]);                          \
                A2[1] = MFMA16(f1, bf[7][1], A2[1]);                          \
                A2[0] = MFMA16(f2, bf[8][0], A2[0]);                          \
                A2[1] = MFMA16(f2, bf[8][1], A2[1]);                          \
                RETIRE(y_ - 2, A2);                                           \
            }                                                                 \
            rp += 1664;                                                       \
        }                                                                     \
    } while (0)

    for (int yb = 0; yb < 27; yb += 3) {
        CSTEP(yb + 0, sl0, sl2, sl1);
        CSTEP(yb + 1, sl1, sl0, sl2);
        CSTEP(yb + 2, sl2, sl1, sl0);
    }
#undef CSTEP
#undef RETIRE
}

// ---------------------------------------------------------------------------
// fc1: C[4096,128] = A[4096,9216](fp16) x W^T. Split-K=16 (chunk 576).
// LDS-free, barrier-free. Grid 32x16 = 512 blocks. fp16 partials.
// ---------------------------------------------------------------------------
__global__ __launch_bounds__(256) void k_fc1(const half_t* __restrict__ A,
                                             const half_t* __restrict__ W,
                                             half_t* __restrict__ part) {
    const int t = threadIdx.x;
    const int mb = blockIdx.x;  // 0..31
    const int kb = blockIdx.y;  // 0..15
    const int w = t >> 6, ln = t & 63, n16 = ln & 15, q = ln >> 4;

    const half_t* a0 = A + (size_t)(mb * 128 + w * 32 + n16) * 9216 + kb * 576 + q * 8;
    const half_t* a1 = a0 + (size_t)16 * 9216;
    const half_t* wp = W + (size_t)n16 * 9216 + kb * 576 + q * 8;

    floatx4 acc[2][8];
#pragma unroll
    for (int s = 0; s < 2; ++s)
#pragma unroll
        for (int nt = 0; nt < 8; ++nt) acc[s][nt] = (floatx4){0.f, 0.f, 0.f, 0.f};

    for (int kt = 0; kt < 18; ++kt) {
        const int ko = kt * 32;
        half8 af0 = *(const half8*)(a0 + ko);
        half8 af1 = *(const half8*)(a1 + ko);
#pragma unroll
        for (int nt = 0; nt < 8; ++nt) {
            half8 bfr = *(const half8*)(wp + (size_t)nt * 16 * 9216 + ko);
            acc[0][nt] = MFMA16(af0, bfr, acc[0][nt]);
            acc[1][nt] = MFMA16(af1, bfr, acc[1][nt]);
        }
    }
    const int rowbase = mb * 128 + w * 32;
#pragma unroll
    for (int s = 0; s < 2; ++s)
#pragma unroll
        for (int nt = 0; nt < 8; ++nt)
#pragma unroll
            for (int r = 0; r < 4; ++r) {
                const int row = rowbase + s * 16 + q * 4 + r;
                const int col = nt * 16 + n16;
                part[(size_t)kb * 524288 + (size_t)row * 128 + col] = (half_t)acc[s][nt][r];
            }
}

// ---------------------------------------------------------------------------
// fc1 split-K reduction + bias + ReLU -> fp16 h3
// ---------------------------------------------------------------------------
__global__ void k_fc1red(const half_t* __restrict__ part, const float* __restrict__ b,
                         half_t* __restrict__ h3) {
    const int idx = blockIdx.x * 256 + threadIdx.x;  // 524288 exact
    const int col = idx & 127;
    float s = 0.0f;
#pragma unroll
    for (int j = 0; j < 16; ++j) s += (float)part[(size_t)j * 524288 + idx];
    s = fmaxf(s + b[col], 0.0f);
    h3[idx] = (half_t)s;
}

// ---------------------------------------------------------------------------
// fc2 + GMM posterior (fp32). One thread per sample.
// ---------------------------------------------------------------------------
__global__ __launch_bounds__(256) void k_fc2gmm(
    const half_t* __restrict__ h3, const float* __restrict__ fw,
    const float* __restrict__ fb, const float* __restrict__ cent,
    const float* __restrict__ Sinv, const float* __restrict__ dets,
    float* __restrict__ out) {
    __shared__ float sw[1280];
    __shared__ float sb[10];
    __shared__ float sc[100];
    __shared__ float ss[1000];
    __shared__ float sd[10];
    const int t = threadIdx.x;
    for (int i = t; i < 1280; i += 256) sw[i] = fw[i];
    if (t < 10) sb[t] = fb[t];
    if (t < 100) sc[t] = cent[t];
    for (int i = t; i < 1000; i += 256) ss[i] = Sinv[i];
    if (t < 10) sd[t] = dets[t];
    __syncthreads();

    const int bidx = blockIdx.x * 256 + t;  // 4096 samples exact
    half2v hh[64];
    const half2v* hp = (const half2v*)(h3 + (size_t)bidx * 128);
#pragma unroll
    for (int i = 0; i < 64; ++i) hh[i] = hp[i];

    float y[10];
#pragma unroll
    for (int o = 0; o < 10; ++o) {
        float a = sb[o];
#pragma unroll
        for (int k = 0; k < 64; ++k) {
            a = fmaf((float)hh[k][0], sw[o * 128 + 2 * k], a);
            a = fmaf((float)hh[k][1], sw[o * 128 + 2 * k + 1], a);
        }
        y[o] = a;
    }

    float expo[10];
    float mx = -3.402823466e38f;
#pragma unroll
    for (int k = 0; k < 10; ++k) {
        float d[10];
#pragma unroll
        for (int j = 0; j < 10; ++j) d[j] = y[j] - sc[k * 10 + j];
        float s = 0.0f;
#pragma unroll
        for (int i = 0; i < 10; ++i) {
            float r = 0.0f;
#pragma unroll
            for (int j = 0; j < 10; ++j) r = fmaf(ss[k * 100 + i * 10 + j], d[j], r);
            s = fmaf(d[i], r, s);
        }
        expo[k] = -0.5f * s;
        mx = fmaxf(mx, expo[k]);
    }
    float num[10];
    float sum = 0.0f;
#pragma unroll
    for (int k = 0; k < 10; ++k) {
        num[k] = sd[k] * __expf(expo[k] - mx);
        sum += num[k];
    }
    const float inv = 1.0f / sum;
#pragma unroll
    for (int k = 0; k < 10; ++k) out[(size_t)bidx * 10 + k] = num[k] * inv;
}

// ---------------------------------------------------------------------------
extern "C" void kernel_launch(void* const* d_in, const int* in_sizes, int n_in,
                              void* d_out, int out_size, void* d_ws, size_t ws_size,
                              hipStream_t stream) {
    const float* x = (const float*)d_in[0];
    const float* w1 = (const float*)d_in[1];
    const float* b1 = (const float*)d_in[2];
    const float* w2 = (const float*)d_in[3];
    const float* b2 = (const float*)d_in[4];
    const float* fw1 = (const float*)d_in[5];
    const float* fb1 = (const float*)d_in[6];
    const float* fw2 = (const float*)d_in[7];
    const float* fb2 = (const float*)d_in[8];
    const float* cen = (const float*)d_in[9];
    const float* raw = (const float*)d_in[10];
    float* out = (float*)d_out;

    char* ws = (char*)d_ws;
    half_t* W2T = (half_t*)(ws);                 //    36,864 B
    half_t* W1h = (half_t*)(ws + 36864);         // 2,359,296 B
    half_t* h2p = (half_t*)(ws + 2396160);       // 75,497,472 B
    half_t* part = (half_t*)(ws + 77893632);     // 16,777,216 B (16 x 524288 fp16)
    half_t* h3h = (half_t*)(ws + 94670848);      // 1,048,576 B
    float* gS = (float*)(ws + 95719424);         //     4,000 B
    float* gD = (float*)(ws + 95723424);         //        40 B  (total ~95.7 MB)

    k_prep<<<4681, 256, 0, stream>>>(fw1, W1h, w2, W2T, raw, gS, gD);
    k_convs<<<4096, 256, 0, stream>>>(x, w1, b1, b2, W2T, h2p);
    k_fc1<<<dim3(32, 16), 256, 0, stream>>>(h2p, W1h, part);
    k_fc1red<<<2048, 256, 0, stream>>>(part, fb1, h3h);
    k_fc2gmm<<<16, 256, 0, stream>>>(h3h, fw2, fb2, cen, gS, gD, out);
}